// Round 1
// baseline (206.329 us; speedup 1.0000x reference)
//
#include <hip/hip_runtime.h>
#include <stdint.h>

#define NUM_P 8732
#define NUM_B 64
#define NUM_CLS 21
#define TOPK 200
#define NMS_T 0.45f
#define CONF_T 0.01f
#define NL 35      // ceil(8732/256)
#define NL2 16     // ceil(4000/256)
#define MAXCAND 4000

__device__ __forceinline__ uint32_t ordf(float f) {
    uint32_t u = __float_as_uint(f);
    return (u & 0x80000000u) ? ~u : (u | 0x80000000u);
}
__device__ __forceinline__ float unordf(uint32_t v) {
    uint32_t u = (v & 0x80000000u) ? (v ^ 0x80000000u) : ~v;
    return __uint_as_float(u);
}

// ---------------- Kernel A: softmax denominators + zero counters ----------------
__global__ __launch_bounds__(256) void prep_kernel(const float* __restrict__ conf,
                                                   float2* __restrict__ denom,
                                                   uint32_t* __restrict__ candCount) {
    int idx = blockIdx.x * 256 + threadIdx.x;
    if (blockIdx.x == 0 && threadIdx.x < NUM_B) candCount[threadIdx.x] = 0u;
    if (idx >= NUM_B * NUM_P) return;
    const float* row = conf + (size_t)idx * NUM_CLS;
    float x[NUM_CLS];
#pragma unroll
    for (int c = 0; c < NUM_CLS; ++c) x[c] = row[c];
    float m = x[0];
#pragma unroll
    for (int c = 1; c < NUM_CLS; ++c) m = fmaxf(m, x[c]);
    float s = 0.0f;
#pragma unroll
    for (int c = 0; c < NUM_CLS; ++c) s += expf(x[c] - m);   // in-order f32 sum
    denom[idx] = make_float2(m, s);
}

// ---------------- Kernel B: per-(image,class) exact top-k + NMS ----------------
__global__ __launch_bounds__(256) void topk_nms_kernel(const float* __restrict__ conf,
                                                       const float* __restrict__ loc,
                                                       const float* __restrict__ priors,
                                                       const float2* __restrict__ denom,
                                                       float* __restrict__ classRows,
                                                       uint64_t* __restrict__ cands,
                                                       uint32_t* __restrict__ candCount) {
    const int blk = blockIdx.x;
    const int b = blk / 20;
    const int c = blk % 20;            // score column = c+1 (skip background)
    const int tid = threadIdx.x;
    const int lane = tid & 63;
    const int wv = tid >> 6;
    const size_t base = (size_t)b * NUM_P;

    // Phase 1: keys in registers (value desc, index asc via ~p)
    uint64_t key[NL];
#pragma unroll
    for (int i = 0; i < NL; ++i) {
        int p = tid + i * 256;
        uint64_t k = 0;
        if (p < NUM_P) {
            float2 ms = denom[base + p];
            float x = conf[(base + p) * NUM_CLS + (c + 1)];
            float sc = expf(x - ms.x) / ms.y;
            float s = (sc > CONF_T) ? sc : -1.0f;
            k = ((uint64_t)ordf(s) << 32) | (uint32_t)(0xFFFFFFFFu - (uint32_t)p);
        }
        key[i] = k;
    }

    // Phase 2: 64-step MSB bit descent for the exact 200th-largest key
    __shared__ int wsum[2][4];
    uint64_t prefix = 0;
    for (int bit = 63; bit >= 0; --bit) {
        uint64_t cand = prefix | (1ull << bit);
        int cnt = 0;
#pragma unroll
        for (int i = 0; i < NL; ++i) cnt += (key[i] >= cand) ? 1 : 0;
        for (int off = 32; off; off >>= 1) cnt += __shfl_down(cnt, off);
        int bufi = bit & 1;
        if (lane == 0) wsum[bufi][wv] = cnt;
        __syncthreads();
        int tot = wsum[bufi][0] + wsum[bufi][1] + wsum[bufi][2] + wsum[bufi][3];
        if (tot >= TOPK) prefix = cand;
    }

    // Phase 3: compact the exactly-200 selected keys into LDS
    __shared__ uint64_t skey[256];
    __shared__ int scnt;
    skey[tid] = 0;
    if (tid == 0) scnt = 0;
    __syncthreads();
#pragma unroll
    for (int i = 0; i < NL; ++i)
        if (key[i] >= prefix) { int s = atomicAdd(&scnt, 1); skey[s] = key[i]; }
    __syncthreads();

    // Phase 4: bitonic sort 256 descending by key
    for (int k = 2; k <= 256; k <<= 1) {
        for (int j = k >> 1; j > 0; j >>= 1) {
            int ixj = tid ^ j;
            if (ixj > tid) {
                uint64_t a = skey[tid], bb = skey[ixj];
                bool up = (tid & k) == 0;              // descending network
                bool sw = up ? (a < bb) : (a > bb);
                if (sw) { skey[tid] = bb; skey[ixj] = a; }
            }
            __syncthreads();
        }
    }

    // Phase 5: decode selected boxes + greedy NMS (matches reference fori_loop)
    __shared__ float bx1[TOPK], by1[TOPK], bx2[TOPK], by2[TOPK], bar[TOPK];
    __shared__ unsigned char bval[TOPK], bsup[TOPK];
    float mx1 = 0, my1 = 0, mx2 = 0, my2 = 0, mar = 0, msc = -1.0f;
    const bool mine = tid < TOPK;
    if (mine) {
        uint64_t k = skey[tid];
        uint32_t p = 0xFFFFFFFFu - (uint32_t)k;
        msc = unordf((uint32_t)(k >> 32));
        const float4 l4 = reinterpret_cast<const float4*>(loc)[base + p];
        const float4 pr = reinterpret_cast<const float4*>(priors)[p];
        float cx = pr.x + (l4.x * 0.1f) * pr.z;
        float cy = pr.y + (l4.y * 0.1f) * pr.w;
        float w  = pr.z * expf(l4.z * 0.2f);
        float h  = pr.w * expf(l4.w * 0.2f);
        mx1 = cx - w * 0.5f;
        my1 = cy - h * 0.5f;
        mx2 = mx1 + w;
        my2 = my1 + h;
        mar = (mx2 - mx1 + 1.0f) * (my2 - my1 + 1.0f);
        bx1[tid] = mx1; by1[tid] = my1; bx2[tid] = mx2; by2[tid] = my2; bar[tid] = mar;
        bval[tid] = (msc > CONF_T) ? 1 : 0;
        bsup[tid] = 0;
    }
    __syncthreads();

    bool supv = false;
    for (int i = 0; i < TOPK; ++i) {
        bool keep_i = bval[i] && !bsup[i];   // supp[i] is final before iter i
        if (keep_i && mine && tid > i) {
            float xx1 = fmaxf(bx1[i], mx1);
            float yy1 = fmaxf(by1[i], my1);
            float xx2 = fminf(bx2[i], mx2);
            float yy2 = fminf(by2[i], my2);
            float w = fmaxf(0.0f, xx2 - xx1 + 1.0f);
            float h = fmaxf(0.0f, yy2 - yy1 + 1.0f);
            float inter = w * h;
            float iou = inter / (bar[i] + mar - inter);
            if (iou > NMS_T) { bsup[tid] = 1; supv = true; }
        }
        __syncthreads();
    }

    // Phase 6: compact kept rows, emit + push per-image candidates
    bool kept = mine && (msc > CONF_T) && !supv;
    uint64_t ball = __ballot(kept);
    __shared__ int wcnt[4];
    if (lane == 0) wcnt[wv] = __popcll(ball);
    __syncthreads();
    int offset = 0;
    for (int w2 = 0; w2 < wv; ++w2) offset += wcnt[w2];
    int myslot = offset + __popcll(ball & ((1ull << lane) - 1ull));
    if (kept) {
        float* row = classRows + (((size_t)blk) * TOPK + myslot) * 5;
        row[0] = msc; row[1] = mx1; row[2] = my1; row[3] = mx2; row[4] = my2;
        uint32_t pos = (uint32_t)(c + 1) * TOPK + (uint32_t)myslot;
        uint64_t k2 = ((uint64_t)ordf(msc) << 32) | (uint32_t)(0xFFFFFFFFu - pos);
        uint32_t ci = atomicAdd(&candCount[b], 1u);
        cands[(size_t)b * MAXCAND + ci] = k2;
    }
}

// ---------------- Kernel C: per-image final top-200, position-ordered ----------------
__global__ __launch_bounds__(256) void final_kernel(const uint64_t* __restrict__ cands,
                                                    const uint32_t* __restrict__ candCount,
                                                    const float* __restrict__ classRows,
                                                    float* __restrict__ out) {
    const int b = blockIdx.x;
    const int tid = threadIdx.x;
    const int lane = tid & 63;
    const int wv = tid >> 6;
    const int n = (int)candCount[b];

    uint64_t key[NL2];
#pragma unroll
    for (int i = 0; i < NL2; ++i) {
        int idx = tid + i * 256;
        key[i] = (idx < n) ? cands[(size_t)b * MAXCAND + idx] : 0ull;
    }

    __shared__ int wsum[2][4];
    uint64_t prefix = 0;
    if (n > TOPK) {
        for (int bit = 63; bit >= 0; --bit) {
            uint64_t cand = prefix | (1ull << bit);
            int cnt = 0;
#pragma unroll
            for (int i = 0; i < NL2; ++i) cnt += (key[i] >= cand) ? 1 : 0;
            for (int off = 32; off; off >>= 1) cnt += __shfl_down(cnt, off);
            int bufi = bit & 1;
            if (lane == 0) wsum[bufi][wv] = cnt;
            __syncthreads();
            int tot = wsum[bufi][0] + wsum[bufi][1] + wsum[bufi][2] + wsum[bufi][3];
            if (tot >= TOPK) prefix = cand;
        }
    }

    __shared__ uint32_t selpos[256];
    __shared__ int scnt;
    selpos[tid] = 0xFFFFFFFFu;
    if (tid == 0) scnt = 0;
    __syncthreads();
#pragma unroll
    for (int i = 0; i < NL2; ++i)
        if (key[i] != 0ull && key[i] >= prefix) {
            int s = atomicAdd(&scnt, 1);
            selpos[s] = 0xFFFFFFFFu - (uint32_t)key[i];
        }
    __syncthreads();
    int nsel = scnt;

    // bitonic sort ascending by position
    for (int k = 2; k <= 256; k <<= 1) {
        for (int j = k >> 1; j > 0; j >>= 1) {
            int ixj = tid ^ j;
            if (ixj > tid) {
                uint32_t a = selpos[tid], bb = selpos[ixj];
                bool up = (tid & k) == 0;
                bool sw = up ? (a > bb) : (a < bb);
                if (sw) { selpos[tid] = bb; selpos[ixj] = a; }
            }
            __syncthreads();
        }
    }

    if (tid < TOPK) {
        int T = TOPK - (nsel < TOPK ? nsel : TOPK);
        float* o = out + ((size_t)b * TOPK + tid) * 7;
        if (tid < T) {
            o[0] = 0.f; o[1] = 0.f; o[2] = 0.f; o[3] = 0.f; o[4] = 0.f; o[5] = 0.f; o[6] = 0.f;
        } else {
            uint32_t pos = selpos[tid - T];
            uint32_t cc = pos / TOPK;
            uint32_t sl = pos % TOPK;
            const float* row = classRows + (((size_t)b * 20 + (cc - 1)) * TOPK + sl) * 5;
            o[0] = row[0]; o[1] = row[1]; o[2] = row[2]; o[3] = row[3]; o[4] = row[4];
            o[5] = 0.f; o[6] = 0.f;
        }
    }
}

extern "C" void kernel_launch(void* const* d_in, const int* in_sizes, int n_in,
                              void* d_out, int out_size, void* d_ws, size_t ws_size,
                              hipStream_t stream) {
    const float* loc    = (const float*)d_in[0];
    const float* conf   = (const float*)d_in[1];
    const float* priors = (const float*)d_in[2];
    float* out = (float*)d_out;

    const size_t DENOM_BYTES = (size_t)NUM_B * NUM_P * sizeof(float2);     // 4,470,784
    const size_t CAND_BYTES  = (size_t)NUM_B * MAXCAND * sizeof(uint64_t); // 2,048,000
    const size_t ROWS_BYTES  = (size_t)NUM_B * 20 * TOPK * 5 * sizeof(float); // 5,120,000

    char* ws = (char*)d_ws;
    float2*   denom     = (float2*)ws;
    uint64_t* cands     = (uint64_t*)(ws + DENOM_BYTES);
    float*    classRows = (float*)(ws + DENOM_BYTES + CAND_BYTES);
    uint32_t* candCount = (uint32_t*)(ws + DENOM_BYTES + CAND_BYTES + ROWS_BYTES);

    int prep_blocks = (NUM_B * NUM_P + 255) / 256;
    prep_kernel<<<prep_blocks, 256, 0, stream>>>(conf, denom, candCount);
    topk_nms_kernel<<<NUM_B * 20, 256, 0, stream>>>(conf, loc, priors, denom,
                                                    classRows, cands, candCount);
    final_kernel<<<NUM_B, 256, 0, stream>>>(cands, candCount, classRows, out);
}

// Round 2
// 167.207 us; speedup vs baseline: 1.2340x; 1.2340x over previous
//
#include <hip/hip_runtime.h>
#include <stdint.h>

#define NUM_P 8732
#define NUM_B 64
#define NUM_CLS 21
#define TOPK 200
#define NMS_T 0.45f
#define CONF_T 0.01f
#define NL 35               // ceil(8732/256)
#define PPAD (256 * NL)     // 8960
#define NL2 16              // ceil(4000/256)
#define MAXCAND 4000
#define BINS 2048
#define ORD_SENT 0x407FFFFFu   // ordf(-1.0f)

__device__ __forceinline__ uint32_t ordf(float f) {
    uint32_t u = __float_as_uint(f);
    return (u & 0x80000000u) ? ~u : (u | 0x80000000u);
}
__device__ __forceinline__ float unordf(uint32_t v) {
    uint32_t u = (v & 0x80000000u) ? (v ^ 0x80000000u) : ~v;
    return __uint_as_float(u);
}

// ---------------- Kernel A: softmax -> transposed score ordinals (or denom fallback) ----
__global__ __launch_bounds__(256) void prep_kernel(const float* __restrict__ conf,
                                                   uint32_t* __restrict__ ct,      // may be null
                                                   float2* __restrict__ denom,     // used if ct==null
                                                   uint32_t* __restrict__ candCount) {
    const int p = blockIdx.x * 256 + threadIdx.x;
    const int b = blockIdx.y;
    if (blockIdx.x == 0 && blockIdx.y == 0 && threadIdx.x < NUM_B) candCount[threadIdx.x] = 0u;
    if (p >= NUM_P) return;
    const float* row = conf + ((size_t)b * NUM_P + p) * NUM_CLS;
    float x[NUM_CLS];
#pragma unroll
    for (int c = 0; c < NUM_CLS; ++c) x[c] = row[c];
    float m = x[0];
#pragma unroll
    for (int c = 1; c < NUM_CLS; ++c) m = fmaxf(m, x[c]);
    float e[NUM_CLS];
    float s = 0.0f;
#pragma unroll
    for (int c = 0; c < NUM_CLS; ++c) { e[c] = expf(x[c] - m); s += e[c]; }  // in-order f32 sum
    if (ct) {
#pragma unroll
        for (int c = 1; c < NUM_CLS; ++c) {
            float sc = e[c] / s;
            float sv = (sc > CONF_T) ? sc : -1.0f;
            ct[((size_t)(b * 20 + (c - 1))) * NUM_P + p] = ordf(sv);   // coalesced per c
        }
    } else {
        denom[(size_t)b * NUM_P + p] = make_float2(m, s);
    }
}

// ---------------- Kernel B: per-(image,class) exact top-200 + NMS ----------------
__global__ __launch_bounds__(256) void topk_nms_kernel(const uint32_t* __restrict__ ct,  // may be null
                                                       const float* __restrict__ conf,
                                                       const float2* __restrict__ denom,
                                                       const float* __restrict__ loc,
                                                       const float* __restrict__ priors,
                                                       float* __restrict__ classRows,
                                                       uint64_t* __restrict__ cands,
                                                       uint32_t* __restrict__ candCount) {
    __shared__ uint32_t ord[PPAD];      // 35840 B
    __shared__ uint32_t hist[BINS];     // 8192 B (reused for NMS arrays later)
    __shared__ uint32_t wtot[4];
    __shared__ uint32_t sh_d, sh_above, sh_nreal;
    __shared__ uint64_t skey[256];
    __shared__ int scnt;
    __shared__ int wcnt[4];

    const int blk = blockIdx.x;
    const int b = blk / 20;
    const int c = blk % 20;             // score column = c+1
    const int tid = threadIdx.x;
    const int lane = tid & 63;
    const int wv = tid >> 6;

#pragma unroll
    for (int i = 0; i < BINS / 256; ++i) hist[tid + i * 256] = 0;
    skey[tid] = 0;
    if (tid == 0) scnt = 0;
    __syncthreads();

    // ---- Phase 1: fill LDS ordinals + histogram (top 11 bits), sentinels excluded ----
    int nsent_local = 0;
    if (ct) {
        const uint32_t* col = ct + (size_t)blk * NUM_P;
#pragma unroll
        for (int i = 0; i < NL; ++i) {
            int p = tid + i * 256;
            uint32_t o = 0;
            if (p < NUM_P) {
                o = col[p];
                if (o == ORD_SENT) nsent_local++;
                else atomicAdd(&hist[o >> 21], 1u);
            }
            ord[p] = o;
        }
    } else {
        const size_t base = (size_t)b * NUM_P;
#pragma unroll
        for (int i = 0; i < NL; ++i) {
            int p = tid + i * 256;
            uint32_t o = 0;
            if (p < NUM_P) {
                float2 ms = denom[base + p];
                float xx = conf[(base + p) * NUM_CLS + (c + 1)];
                float sc = expf(xx - ms.x) / ms.y;
                float sv = (sc > CONF_T) ? sc : -1.0f;
                o = ordf(sv);
                if (o == ORD_SENT) nsent_local++;
                else atomicAdd(&hist[o >> 21], 1u);
            }
            ord[p] = o;
        }
    }
    // block-reduce sentinel count
    {
        int v = nsent_local;
#pragma unroll
        for (int off = 32; off; off >>= 1) v += __shfl_down(v, off);
        if (lane == 0) wtot[wv] = (uint32_t)v;
        __syncthreads();
        if (tid == 0) sh_nreal = (uint32_t)(NUM_P - (int)(wtot[0] + wtot[1] + wtot[2] + wtot[3]));
        __syncthreads();
    }
    const int nreal = (int)sh_nreal;

    uint32_t prefix;
    int need;

    if (nreal >= TOPK) {
        // ---- 3-pass radix select over non-sentinel ordinals ----
        prefix = 0;
        uint32_t pmask = 0;
        need = TOPK;
        const int shifts[3] = {21, 10, 0};
        const int nbin[3] = {2048, 2048, 1024};
#pragma unroll
        for (int pass = 0; pass < 3; ++pass) {
            const int sh = shifts[pass];
            const int nb = nbin[pass];
            const uint32_t dmask = (uint32_t)(nb - 1);
            if (pass > 0) {
#pragma unroll
                for (int i = 0; i < BINS / 256; ++i) hist[tid + i * 256] = 0;
                __syncthreads();
#pragma unroll
                for (int i = 0; i < NL; ++i) {
                    uint32_t o = ord[tid + i * 256];
                    if (o != ORD_SENT && o != 0u && (o & pmask) == prefix)
                        atomicAdd(&hist[(o >> sh) & dmask], 1u);
                }
                __syncthreads();
            }
            // per-thread bin range sums (ascending bins with tid)
            const int bpt = nb / 256;
            const int tbase = tid * bpt;
            uint32_t ls = 0;
            for (int j = 0; j < bpt; ++j) ls += hist[tbase + j];
            // wave-level inclusive suffix scan
            uint32_t v = ls;
#pragma unroll
            for (int off = 1; off < 64; off <<= 1) {
                uint32_t o2 = __shfl_down(v, off);
                if (lane + off < 64) v += o2;
            }
            if (lane == 0) wtot[wv] = v;   // wave total
            __syncthreads();
            uint32_t above_wave = 0;
            for (int w = wv + 1; w < 4; ++w) above_wave += wtot[w];
            uint32_t v_incl = v + above_wave;      // suffix incl my bins
            uint32_t acc = v_incl - ls;            // strictly above my bins
            for (int j = bpt - 1; j >= 0; --j) {
                uint32_t h = hist[tbase + j];
                if (acc < (uint32_t)need && acc + h >= (uint32_t)need) {
                    sh_d = (uint32_t)(tbase + j);
                    sh_above = acc;
                }
                acc += h;
            }
            __syncthreads();
            need -= (int)sh_above;
            prefix |= (sh_d << sh);
            pmask |= (dmask << sh);
            __syncthreads();
        }
    } else {
        // fewer than 200 real scores: take all reals + lowest-p sentinels
        prefix = ORD_SENT;
        need = TOPK - nreal;
    }

    // ---- Selection emit: all ord > prefix, plus first `need` matches (p ascending) ----
    const int lo = tid * NL;    // contiguous chunk [lo, lo+NL) in p order
    int m = 0;
#pragma unroll
    for (int i = 0; i < NL; ++i) m += (ord[lo + i] == prefix) ? 1 : 0;
    {
        uint32_t v = (uint32_t)m;
#pragma unroll
        for (int off = 1; off < 64; off <<= 1) {
            uint32_t o2 = __shfl_up(v, off);
            if (lane >= off) v += o2;
        }
        if (lane == 63) wtot[wv] = v;   // wave inclusive total
        __syncthreads();
        uint32_t woff = 0;
        for (int w = 0; w < wv; ++w) woff += wtot[w];
        int mybase = (int)(woff + v) - m;   // exclusive rank base
        int r = 0;
        for (int i = 0; i < NL; ++i) {
            int p = lo + i;
            uint32_t o = ord[p];
            bool sel = false;
            if (o > prefix) sel = true;
            else if (o == prefix) { sel = (mybase + r) < need; r++; }
            if (sel && p < NUM_P) {
                int s0 = atomicAdd(&scnt, 1);
                skey[s0] = ((uint64_t)o << 32) | (uint32_t)(0xFFFFFFFFu - (uint32_t)p);
            }
        }
    }
    __syncthreads();

    // ---- Bitonic sort 256 descending by key ----
    for (int k = 2; k <= 256; k <<= 1) {
        for (int j = k >> 1; j > 0; j >>= 1) {
            int ixj = tid ^ j;
            if (ixj > tid) {
                uint64_t a = skey[tid], bb = skey[ixj];
                bool up = (tid & k) == 0;
                bool sw = up ? (a < bb) : (a > bb);
                if (sw) { skey[tid] = bb; skey[ixj] = a; }
            }
            __syncthreads();
        }
    }

    // ---- Decode + greedy NMS (reference fori_loop semantics) ----
    float* nbuf = reinterpret_cast<float*>(hist);   // hist dead; 8192 B >= 4512 B
    float* bx1 = nbuf;
    float* by1 = nbuf + TOPK;
    float* bx2 = nbuf + 2 * TOPK;
    float* by2 = nbuf + 3 * TOPK;
    float* bar = nbuf + 4 * TOPK;
    unsigned char* bval = (unsigned char*)(nbuf + 5 * TOPK);
    unsigned char* bsup = bval + 256;

    float mx1 = 0, my1 = 0, mx2 = 0, my2 = 0, mar = 0, msc = -1.0f;
    const bool mine = tid < TOPK;
    const size_t base = (size_t)b * NUM_P;
    if (mine) {
        uint64_t k = skey[tid];
        uint32_t p = 0xFFFFFFFFu - (uint32_t)k;
        msc = unordf((uint32_t)(k >> 32));
        const float4 l4 = reinterpret_cast<const float4*>(loc)[base + p];
        const float4 pr = reinterpret_cast<const float4*>(priors)[p];
        float cx = pr.x + (l4.x * 0.1f) * pr.z;
        float cy = pr.y + (l4.y * 0.1f) * pr.w;
        float w  = pr.z * expf(l4.z * 0.2f);
        float h  = pr.w * expf(l4.w * 0.2f);
        mx1 = cx - w * 0.5f;
        my1 = cy - h * 0.5f;
        mx2 = mx1 + w;
        my2 = my1 + h;
        mar = (mx2 - mx1 + 1.0f) * (my2 - my1 + 1.0f);
        bx1[tid] = mx1; by1[tid] = my1; bx2[tid] = mx2; by2[tid] = my2; bar[tid] = mar;
        bval[tid] = (msc > CONF_T) ? 1 : 0;
        bsup[tid] = 0;
    }
    __syncthreads();

    bool supv = false;
    for (int i = 0; i < TOPK; ++i) {
        bool keep_i = bval[i] && !bsup[i];
        if (keep_i && mine && tid > i) {
            float xx1 = fmaxf(bx1[i], mx1);
            float yy1 = fmaxf(by1[i], my1);
            float xx2 = fminf(bx2[i], mx2);
            float yy2 = fminf(by2[i], my2);
            float w = fmaxf(0.0f, xx2 - xx1 + 1.0f);
            float h = fmaxf(0.0f, yy2 - yy1 + 1.0f);
            float inter = w * h;
            float iou = inter / (bar[i] + mar - inter);
            if (iou > NMS_T) { bsup[tid] = 1; supv = true; }
        }
        __syncthreads();
    }

    // ---- Compact kept rows, emit + push per-image candidates ----
    bool kept = mine && (msc > CONF_T) && !supv;
    uint64_t ball = __ballot(kept);
    if (lane == 0) wcnt[wv] = __popcll(ball);
    __syncthreads();
    int offset = 0;
    for (int w2 = 0; w2 < wv; ++w2) offset += wcnt[w2];
    int myslot = offset + __popcll(ball & ((1ull << lane) - 1ull));
    if (kept) {
        float* row = classRows + (((size_t)blk) * TOPK + myslot) * 5;
        row[0] = msc; row[1] = mx1; row[2] = my1; row[3] = mx2; row[4] = my2;
        uint32_t pos = (uint32_t)(c + 1) * TOPK + (uint32_t)myslot;
        uint64_t k2 = ((uint64_t)ordf(msc) << 32) | (uint32_t)(0xFFFFFFFFu - pos);
        uint32_t ci = atomicAdd(&candCount[b], 1u);
        cands[(size_t)b * MAXCAND + ci] = k2;
    }
}

// ---------------- Kernel C: per-image final top-200, position-ordered ----------------
__global__ __launch_bounds__(256) void final_kernel(const uint64_t* __restrict__ cands,
                                                    const uint32_t* __restrict__ candCount,
                                                    const float* __restrict__ classRows,
                                                    float* __restrict__ out) {
    const int b = blockIdx.x;
    const int tid = threadIdx.x;
    const int lane = tid & 63;
    const int wv = tid >> 6;
    const int n = (int)candCount[b];

    uint64_t key[NL2];
#pragma unroll
    for (int i = 0; i < NL2; ++i) {
        int idx = tid + i * 256;
        key[i] = (idx < n) ? cands[(size_t)b * MAXCAND + idx] : 0ull;
    }

    __shared__ int wsum[2][4];
    uint64_t prefix = 0;
    if (n > TOPK) {
        for (int bit = 63; bit >= 0; --bit) {
            uint64_t cand = prefix | (1ull << bit);
            int cnt = 0;
#pragma unroll
            for (int i = 0; i < NL2; ++i) cnt += (key[i] >= cand) ? 1 : 0;
            for (int off = 32; off; off >>= 1) cnt += __shfl_down(cnt, off);
            int bufi = bit & 1;
            if (lane == 0) wsum[bufi][wv] = cnt;
            __syncthreads();
            int tot = wsum[bufi][0] + wsum[bufi][1] + wsum[bufi][2] + wsum[bufi][3];
            if (tot >= TOPK) prefix = cand;
        }
    }

    __shared__ uint32_t selpos[256];
    __shared__ int scnt;
    selpos[tid] = 0xFFFFFFFFu;
    if (tid == 0) scnt = 0;
    __syncthreads();
#pragma unroll
    for (int i = 0; i < NL2; ++i)
        if (key[i] != 0ull && key[i] >= prefix) {
            int s = atomicAdd(&scnt, 1);
            selpos[s] = 0xFFFFFFFFu - (uint32_t)key[i];
        }
    __syncthreads();
    int nsel = scnt;

    for (int k = 2; k <= 256; k <<= 1) {
        for (int j = k >> 1; j > 0; j >>= 1) {
            int ixj = tid ^ j;
            if (ixj > tid) {
                uint32_t a = selpos[tid], bb = selpos[ixj];
                bool up = (tid & k) == 0;
                bool sw = up ? (a > bb) : (a < bb);
                if (sw) { selpos[tid] = bb; selpos[ixj] = a; }
            }
            __syncthreads();
        }
    }

    if (tid < TOPK) {
        int T = TOPK - (nsel < TOPK ? nsel : TOPK);
        float* o = out + ((size_t)b * TOPK + tid) * 7;
        if (tid < T) {
            o[0] = 0.f; o[1] = 0.f; o[2] = 0.f; o[3] = 0.f; o[4] = 0.f; o[5] = 0.f; o[6] = 0.f;
        } else {
            uint32_t pos = selpos[tid - T];
            uint32_t cc = pos / TOPK;
            uint32_t sl = pos % TOPK;
            const float* row = classRows + (((size_t)b * 20 + (cc - 1)) * TOPK + sl) * 5;
            o[0] = row[0]; o[1] = row[1]; o[2] = row[2]; o[3] = row[3]; o[4] = row[4];
            o[5] = 0.f; o[6] = 0.f;
        }
    }
}

extern "C" void kernel_launch(void* const* d_in, const int* in_sizes, int n_in,
                              void* d_out, int out_size, void* d_ws, size_t ws_size,
                              hipStream_t stream) {
    const float* loc    = (const float*)d_in[0];
    const float* conf   = (const float*)d_in[1];
    const float* priors = (const float*)d_in[2];
    float* out = (float*)d_out;

    const size_t CAND_BYTES  = (size_t)NUM_B * MAXCAND * sizeof(uint64_t);      // 2,048,000
    const size_t ROWS_BYTES  = (size_t)NUM_B * 20 * TOPK * 5 * sizeof(float);   // 5,120,000
    const size_t CNT_BYTES   = 256;
    const size_t CT_BYTES    = (size_t)NUM_B * 20 * NUM_P * sizeof(uint32_t);   // 44,707,840
    const size_t DEN_BYTES   = (size_t)NUM_B * NUM_P * sizeof(float2);          // 4,470,784

    char* ws = (char*)d_ws;
    uint64_t* cands     = (uint64_t*)ws;
    float*    classRows = (float*)(ws + CAND_BYTES);
    uint32_t* candCount = (uint32_t*)(ws + CAND_BYTES + ROWS_BYTES);
    char*     big       = ws + CAND_BYTES + ROWS_BYTES + CNT_BYTES;

    const bool useT = ws_size >= CAND_BYTES + ROWS_BYTES + CNT_BYTES + CT_BYTES;
    uint32_t* ct    = useT ? (uint32_t*)big : nullptr;
    float2*   denom = useT ? nullptr : (float2*)big;

    dim3 pgrid((NUM_P + 255) / 256, NUM_B);
    prep_kernel<<<pgrid, 256, 0, stream>>>(conf, ct, denom, candCount);
    topk_nms_kernel<<<NUM_B * 20, 256, 0, stream>>>(ct, conf, denom, loc, priors,
                                                    classRows, cands, candCount);
    final_kernel<<<NUM_B, 256, 0, stream>>>(cands, candCount, classRows, out);
}

// Round 3
// 96.936 us; speedup vs baseline: 2.1285x; 1.7249x over previous
//
#include <hip/hip_runtime.h>
#include <stdint.h>

#define NUM_P 8732
#define NUM_B 64
#define NUM_CLS 21
#define TOPK 200
#define NMS_T 0.45f
#define CONF_T 0.01f
#define NL 35               // ceil(8732/256)
#define NL2 16              // ceil(4000/256)
#define MAXCAND 4000
#define ORD_SENT 0x407FFFFFu   // ordf(-1.0f)

__device__ __forceinline__ uint32_t ordf(float f) {
    uint32_t u = __float_as_uint(f);
    return (u & 0x80000000u) ? ~u : (u | 0x80000000u);
}
__device__ __forceinline__ float unordf(uint32_t v) {
    uint32_t u = (v & 0x80000000u) ? (v ^ 0x80000000u) : ~v;
    return __uint_as_float(u);
}

// ---------------- Kernel A: softmax -> transposed score ordinals ----------------
__global__ __launch_bounds__(256) void prep_kernel(const float* __restrict__ conf,
                                                   uint32_t* __restrict__ ct,
                                                   uint32_t* __restrict__ candCount) {
    const int p = blockIdx.x * 256 + threadIdx.x;
    const int b = blockIdx.y;
    if (blockIdx.x == 0 && b == 0 && threadIdx.x < NUM_B) candCount[threadIdx.x] = 0u;
    if (p >= NUM_P) return;
    const float* row = conf + ((size_t)b * NUM_P + p) * NUM_CLS;
    float x[NUM_CLS];
#pragma unroll
    for (int c = 0; c < NUM_CLS; ++c) x[c] = row[c];
    float m = x[0];
#pragma unroll
    for (int c = 1; c < NUM_CLS; ++c) m = fmaxf(m, x[c]);
    float e[NUM_CLS];
    float s = 0.0f;
#pragma unroll
    for (int c = 0; c < NUM_CLS; ++c) { e[c] = expf(x[c] - m); s += e[c]; }  // in-order f32 sum
#pragma unroll
    for (int c = 1; c < NUM_CLS; ++c) {
        float sc = e[c] / s;
        float sv = (sc > CONF_T) ? sc : -1.0f;
        ct[((size_t)(b * 20 + (c - 1))) * NUM_P + p] = ordf(sv);   // coalesced per c
    }
}

// ---------------- Kernel B: per-(image,class) exact top-200 + decode ----------------
__global__ __launch_bounds__(256) void select_kernel(const uint32_t* __restrict__ ct,
                                                     const float* __restrict__ loc,
                                                     const float* __restrict__ priors,
                                                     float* __restrict__ selS,
                                                     float* __restrict__ selX1,
                                                     float* __restrict__ selY1,
                                                     float* __restrict__ selX2,
                                                     float* __restrict__ selY2) {
    __shared__ uint32_t hist[2048];
    __shared__ uint32_t wtot[4];
    __shared__ uint32_t sh_d, sh_above, sh_nsent;
    __shared__ uint64_t skey[256];
    __shared__ int scnt;
    __shared__ int sh_run;

    const int blk = blockIdx.x;
    const int b = blk / 20;
    const int tid = threadIdx.x;
    const int lane = tid & 63;
    const int wv = tid >> 6;
    const uint32_t* col = ct + (size_t)blk * NUM_P;

#pragma unroll
    for (int i = 0; i < 8; ++i) hist[tid + i * 256] = 0;
    skey[tid] = 0;
    if (tid == 0) { scnt = 0; sh_run = 0; }
    __syncthreads();

    // ---- pass 1: histogram of top 11 bits + sentinel count ----
    int nsent = 0;
#pragma unroll
    for (int i = 0; i < NL; ++i) {
        int p = tid + i * 256;
        if (p < NUM_P) {
            uint32_t o = col[p];
            if (o == ORD_SENT) nsent++;
            else atomicAdd(&hist[o >> 21], 1u);
        }
    }
    {
        int v = nsent;
#pragma unroll
        for (int off = 32; off; off >>= 1) v += __shfl_down(v, off);
        if (lane == 0) wtot[wv] = (uint32_t)v;
        __syncthreads();
        if (tid == 0) sh_nsent = wtot[0] + wtot[1] + wtot[2] + wtot[3];
        __syncthreads();
    }
    const int nreal = NUM_P - (int)sh_nsent;

    uint32_t prefix = 0, pmask = 0;
    int need;
    if (nreal >= TOPK) {
        need = TOPK;
        const int shifts[3] = {21, 10, 0};
        const int nbins[3] = {2048, 2048, 1024};
        for (int pass = 0; pass < 3; ++pass) {
            const int sh = shifts[pass];
            const int nb = nbins[pass];
            const uint32_t dm = (uint32_t)(nb - 1);
            if (pass > 0) {
#pragma unroll
                for (int i = 0; i < 8; ++i) hist[tid + i * 256] = 0;
                __syncthreads();
#pragma unroll
                for (int i = 0; i < NL; ++i) {
                    int p = tid + i * 256;
                    if (p < NUM_P) {
                        uint32_t o = col[p];
                        if (o != ORD_SENT && (o & pmask) == prefix)
                            atomicAdd(&hist[(o >> sh) & dm], 1u);
                    }
                }
            }
            __syncthreads();
            const int bpt = nb / 256;
            const int tbase = tid * bpt;
            uint32_t ls = 0;
            for (int j = 0; j < bpt; ++j) ls += hist[tbase + j];
            uint32_t v = ls;
#pragma unroll
            for (int off = 1; off < 64; off <<= 1) {
                uint32_t o2 = __shfl_down(v, off);
                if (lane + off < 64) v += o2;
            }
            if (lane == 0) wtot[wv] = v;
            __syncthreads();
            uint32_t above_wave = 0;
            for (int w = wv + 1; w < 4; ++w) above_wave += wtot[w];
            uint32_t acc = (v + above_wave) - ls;   // strictly above my bins
            for (int j = bpt - 1; j >= 0; --j) {
                uint32_t h = hist[tbase + j];
                if (acc < (uint32_t)need && acc + h >= (uint32_t)need) {
                    sh_d = (uint32_t)(tbase + j);
                    sh_above = acc;
                }
                acc += h;
            }
            __syncthreads();
            need -= (int)sh_above;
            prefix |= (sh_d << sh);
            pmask |= (dm << sh);
            __syncthreads();
        }
    } else {
        prefix = ORD_SENT;
        need = TOPK - nreal;
    }

    // ---- emit all o >= prefix (certain + tie candidates) ----
#pragma unroll
    for (int i = 0; i < NL; ++i) {
        int p = tid + i * 256;
        if (p < NUM_P) {
            uint32_t o = col[p];
            if (o >= prefix) {
                int s0 = atomicAdd(&scnt, 1);
                if (s0 < 256)
                    skey[s0] = ((uint64_t)o << 32) | (uint32_t)(0xFFFFFFFFu - (uint32_t)p);
            }
        }
    }
    __syncthreads();

    if (scnt > 256) {
        // rare fallback: ordered scan, exact tie resolution by ascending p
        skey[tid] = 0;
        __syncthreads();
        if (tid == 0) { scnt = 0; sh_run = 0; }
        __syncthreads();
        for (int i = 0; i < NL; ++i) {
            int p = tid + i * 256;
            uint32_t o = (p < NUM_P) ? col[p] : 0u;
            bool cert = (o > prefix);
            bool tie = (o == prefix) && (p < NUM_P);
            if (cert) {
                int s0 = atomicAdd(&scnt, 1);
                skey[s0] = ((uint64_t)o << 32) | (uint32_t)(0xFFFFFFFFu - (uint32_t)p);
            }
            unsigned long long ball = __ballot(tie);
            if (lane == 0) wtot[wv] = (uint32_t)__popcll(ball);
            __syncthreads();
            int rank = sh_run;
            for (int w = 0; w < wv; ++w) rank += (int)wtot[w];
            rank += __popcll(ball & ((1ull << lane) - 1ull));
            if (tie && rank < need) {
                int s0 = atomicAdd(&scnt, 1);
                skey[s0] = ((uint64_t)o << 32) | (uint32_t)(0xFFFFFFFFu - (uint32_t)p);
            }
            __syncthreads();
            if (tid == 0) sh_run += (int)(wtot[0] + wtot[1] + wtot[2] + wtot[3]);
            __syncthreads();
        }
    }

    // ---- bitonic sort 256 descending by key ----
    for (int k = 2; k <= 256; k <<= 1) {
        for (int j = k >> 1; j > 0; j >>= 1) {
            int ixj = tid ^ j;
            if (ixj > tid) {
                uint64_t a = skey[tid], bb = skey[ixj];
                bool up = (tid & k) == 0;
                bool sw = up ? (a < bb) : (a > bb);
                if (sw) { skey[tid] = bb; skey[ixj] = a; }
            }
            __syncthreads();
        }
    }

    // ---- decode top-200 boxes, write SoA ----
    if (tid < TOPK) {
        uint64_t k = skey[tid];
        uint32_t p = 0xFFFFFFFFu - (uint32_t)k;
        float msc = unordf((uint32_t)(k >> 32));
        const float4 l4 = reinterpret_cast<const float4*>(loc)[(size_t)b * NUM_P + p];
        const float4 pr = reinterpret_cast<const float4*>(priors)[p];
        float cx = pr.x + (l4.x * 0.1f) * pr.z;
        float cy = pr.y + (l4.y * 0.1f) * pr.w;
        float w  = pr.z * expf(l4.z * 0.2f);
        float h  = pr.w * expf(l4.w * 0.2f);
        float mx1 = cx - w * 0.5f;
        float my1 = cy - h * 0.5f;
        float mx2 = mx1 + w;
        float my2 = my1 + h;
        size_t o0 = (size_t)blk * TOPK + tid;
        selS[o0] = msc; selX1[o0] = mx1; selY1[o0] = my1; selX2[o0] = mx2; selY2[o0] = my2;
    }
}

// ---------------- Kernel C: one wave per (b,c), register NMS, zero barriers ----------------
__global__ __launch_bounds__(64) void nms_kernel(float* __restrict__ selS,
                                                 float* __restrict__ selX1,
                                                 float* __restrict__ selY1,
                                                 float* __restrict__ selX2,
                                                 float* __restrict__ selY2,
                                                 uint64_t* __restrict__ cands,
                                                 uint32_t* __restrict__ candCount) {
    const int blk = blockIdx.x;
    const int b = blk / 20;
    const int c = blk % 20;
    const int lane = threadIdx.x;
    const size_t base = (size_t)blk * TOPK;

    float scs[4], x1s[4], y1s[4], x2s[4], y2s[4], ars[4];
    uint32_t validm = 0, supm = 0;
#pragma unroll
    for (int s = 0; s < 4; ++s) {
        int idx = s * 64 + lane;
        bool v = idx < TOPK;
        scs[s] = v ? selS[base + idx] : -1.0f;
        x1s[s] = v ? selX1[base + idx] : 0.0f;
        y1s[s] = v ? selY1[base + idx] : 0.0f;
        x2s[s] = v ? selX2[base + idx] : 0.0f;
        y2s[s] = v ? selY2[base + idx] : 0.0f;
        ars[s] = (x2s[s] - x1s[s] + 1.0f) * (y2s[s] - y1s[s] + 1.0f);
        if (v && scs[s] > CONF_T) validm |= (1u << s);
    }

    // greedy NMS in score order; wave-lockstep, no barriers
#pragma unroll
    for (int slot = 0; slot < 4; ++slot) {
        const int nown = (slot == 3) ? (TOPK - 3 * 64) : 64;   // 200 = 3*64 + 8
        for (int owner = 0; owner < nown; ++owner) {
            const int i = slot * 64 + owner;
            int myk = (int)((validm >> slot) & 1u) & (int)(((supm >> slot) & 1u) ^ 1u);
            int keep_i = __shfl(myk, owner);
            if (keep_i) {   // wave-uniform branch
                float bx1 = __shfl(x1s[slot], owner);
                float by1 = __shfl(y1s[slot], owner);
                float bx2 = __shfl(x2s[slot], owner);
                float by2 = __shfl(y2s[slot], owner);
                float bar_ = __shfl(ars[slot], owner);
#pragma unroll
                for (int s2 = 0; s2 < 4; ++s2) {
                    int idx = s2 * 64 + lane;
                    if (idx > i && idx < TOPK) {
                        float xx1 = fmaxf(bx1, x1s[s2]);
                        float yy1 = fmaxf(by1, y1s[s2]);
                        float xx2 = fminf(bx2, x2s[s2]);
                        float yy2 = fminf(by2, y2s[s2]);
                        float w = fmaxf(0.0f, xx2 - xx1 + 1.0f);
                        float h = fmaxf(0.0f, yy2 - yy1 + 1.0f);
                        float inter = w * h;
                        float iou = inter / (bar_ + ars[s2] - inter);
                        if (iou > NMS_T) supm |= (1u << s2);
                    }
                }
            }
        }
    }

    // compact kept rows in index order, in place (all data already in registers)
    int off = 0;
    uint64_t wkey[4];
    int wrank[4];
    bool wk[4];
#pragma unroll
    for (int s = 0; s < 4; ++s) {
        int idx = s * 64 + lane;
        bool kept = (idx < TOPK) && ((validm >> s) & 1u) && !((supm >> s) & 1u);
        unsigned long long ball = __ballot(kept);
        int rank = off + __popcll(ball & ((1ull << lane) - 1ull));
        wk[s] = kept;
        wrank[s] = rank;
        wkey[s] = 0;
        if (kept) {
            selS[base + rank] = scs[s];
            selX1[base + rank] = x1s[s];
            selY1[base + rank] = y1s[s];
            selX2[base + rank] = x2s[s];
            selY2[base + rank] = y2s[s];
            uint32_t pos = (uint32_t)(c + 1) * TOPK + (uint32_t)rank;
            wkey[s] = ((uint64_t)ordf(scs[s]) << 32) | (uint32_t)(0xFFFFFFFFu - pos);
        }
        off += __popcll(ball);
    }
    uint32_t bcast = 0;
    if (lane == 0) bcast = atomicAdd(&candCount[b], (uint32_t)off);
    bcast = (uint32_t)__shfl((int)bcast, 0);
#pragma unroll
    for (int s = 0; s < 4; ++s)
        if (wk[s]) cands[(size_t)b * MAXCAND + bcast + wrank[s]] = wkey[s];
}

// ---------------- Kernel D: per-image final top-200, position-ordered ----------------
__global__ __launch_bounds__(256) void final_kernel(const uint64_t* __restrict__ cands,
                                                    const uint32_t* __restrict__ candCount,
                                                    const float* __restrict__ selS,
                                                    const float* __restrict__ selX1,
                                                    const float* __restrict__ selY1,
                                                    const float* __restrict__ selX2,
                                                    const float* __restrict__ selY2,
                                                    float* __restrict__ out) {
    const int b = blockIdx.x;
    const int tid = threadIdx.x;
    const int lane = tid & 63;
    const int wv = tid >> 6;
    const int n = (int)candCount[b];

    uint64_t key[NL2];
#pragma unroll
    for (int i = 0; i < NL2; ++i) {
        int idx = tid + i * 256;
        key[i] = (idx < n) ? cands[(size_t)b * MAXCAND + idx] : 0ull;
    }

    __shared__ int wsum[2][4];
    uint64_t prefix = 0;
    if (n > TOPK) {
        for (int bit = 63; bit >= 0; --bit) {
            uint64_t cand = prefix | (1ull << bit);
            int cnt = 0;
#pragma unroll
            for (int i = 0; i < NL2; ++i) cnt += (key[i] >= cand) ? 1 : 0;
            for (int off = 32; off; off >>= 1) cnt += __shfl_down(cnt, off);
            int bufi = bit & 1;
            if (lane == 0) wsum[bufi][wv] = cnt;
            __syncthreads();
            int tot = wsum[bufi][0] + wsum[bufi][1] + wsum[bufi][2] + wsum[bufi][3];
            if (tot >= TOPK) prefix = cand;
        }
    }

    __shared__ uint32_t selpos[256];
    __shared__ int scnt;
    selpos[tid] = 0xFFFFFFFFu;
    if (tid == 0) scnt = 0;
    __syncthreads();
#pragma unroll
    for (int i = 0; i < NL2; ++i)
        if (key[i] != 0ull && key[i] >= prefix) {
            int s = atomicAdd(&scnt, 1);
            selpos[s] = 0xFFFFFFFFu - (uint32_t)key[i];
        }
    __syncthreads();
    int nsel = scnt;

    for (int k = 2; k <= 256; k <<= 1) {
        for (int j = k >> 1; j > 0; j >>= 1) {
            int ixj = tid ^ j;
            if (ixj > tid) {
                uint32_t a = selpos[tid], bb = selpos[ixj];
                bool up = (tid & k) == 0;
                bool sw = up ? (a > bb) : (a < bb);
                if (sw) { selpos[tid] = bb; selpos[ixj] = a; }
            }
            __syncthreads();
        }
    }

    if (tid < TOPK) {
        int T = TOPK - (nsel < TOPK ? nsel : TOPK);
        float* o = out + ((size_t)b * TOPK + tid) * 7;
        if (tid < T) {
            o[0] = 0.f; o[1] = 0.f; o[2] = 0.f; o[3] = 0.f; o[4] = 0.f; o[5] = 0.f; o[6] = 0.f;
        } else {
            uint32_t pos = selpos[tid - T];
            uint32_t cc = pos / TOPK;
            uint32_t sl = pos % TOPK;
            size_t r = ((size_t)b * 20 + (cc - 1)) * TOPK + sl;
            o[0] = selS[r]; o[1] = selX1[r]; o[2] = selY1[r]; o[3] = selX2[r]; o[4] = selY2[r];
            o[5] = 0.f; o[6] = 0.f;
        }
    }
}

extern "C" void kernel_launch(void* const* d_in, const int* in_sizes, int n_in,
                              void* d_out, int out_size, void* d_ws, size_t ws_size,
                              hipStream_t stream) {
    const float* loc    = (const float*)d_in[0];
    const float* conf   = (const float*)d_in[1];
    const float* priors = (const float*)d_in[2];
    float* out = (float*)d_out;

    const size_t CAND_BYTES = (size_t)NUM_B * MAXCAND * sizeof(uint64_t);   // 2,048,000
    const size_t SEL_ONE    = (size_t)NUM_B * 20 * TOPK * sizeof(float);    // 1,024,000
    const size_t CNT_BYTES  = 256;

    char* ws = (char*)d_ws;
    uint64_t* cands     = (uint64_t*)ws;
    float*    selS      = (float*)(ws + CAND_BYTES);
    float*    selX1     = (float*)(ws + CAND_BYTES + SEL_ONE);
    float*    selY1     = (float*)(ws + CAND_BYTES + 2 * SEL_ONE);
    float*    selX2     = (float*)(ws + CAND_BYTES + 3 * SEL_ONE);
    float*    selY2     = (float*)(ws + CAND_BYTES + 4 * SEL_ONE);
    uint32_t* candCount = (uint32_t*)(ws + CAND_BYTES + 5 * SEL_ONE);
    uint32_t* ct        = (uint32_t*)(ws + CAND_BYTES + 5 * SEL_ONE + CNT_BYTES);

    dim3 pgrid((NUM_P + 255) / 256, NUM_B);
    prep_kernel<<<pgrid, 256, 0, stream>>>(conf, ct, candCount);
    select_kernel<<<NUM_B * 20, 256, 0, stream>>>(ct, loc, priors,
                                                  selS, selX1, selY1, selX2, selY2);
    nms_kernel<<<NUM_B * 20, 64, 0, stream>>>(selS, selX1, selY1, selX2, selY2,
                                              cands, candCount);
    final_kernel<<<NUM_B, 256, 0, stream>>>(cands, candCount,
                                            selS, selX1, selY1, selX2, selY2, out);
}

// Round 4
// 79.454 us; speedup vs baseline: 2.5968x; 1.2200x over previous
//
#include <hip/hip_runtime.h>
#include <stdint.h>

#define NUM_P 8732
#define NUM_B 64
#define NUM_CLS 21
#define TOPK 200
#define NMS_T 0.45f
#define CONF_T 0.01f
#define NL 35               // ceil(8732/256) scalar sweep iters
#define NV4 2183            // 8732/4 uint4 sweep elements
#define NL2 16              // ceil(4000/256)
#define MAXCAND 4000
#define ORD_SENT 0x407FFFFFu   // ordf(-1.0f)
#define HI_BITS 0x17800u       // (o>>15) high part common to all real scores (o>>26==47)

__device__ __forceinline__ uint32_t ordf(float f) {
    uint32_t u = __float_as_uint(f);
    return (u & 0x80000000u) ? ~u : (u | 0x80000000u);
}
__device__ __forceinline__ float unordf(uint32_t v) {
    uint32_t u = (v & 0x80000000u) ? (v ^ 0x80000000u) : ~v;
    return __uint_as_float(u);
}

// ---------------- Kernel A: softmax -> transposed score ordinals (LDS-staged) --------
__global__ __launch_bounds__(256) void prep_kernel(const float* __restrict__ conf,
                                                   uint32_t* __restrict__ ct,
                                                   uint32_t* __restrict__ candCount) {
    __shared__ float tile[256 * NUM_CLS];   // 21504 B
    const int bx = blockIdx.x;
    const int b = blockIdx.y;
    const int tid = threadIdx.x;
    if (bx == 0 && b == 0 && tid < NUM_B) candCount[tid] = 0u;
    const int p0 = bx * 256;
    const int np = min(256, NUM_P - p0);
    const int nf4 = (np * NUM_CLS) / 4;     // 1344 or 147 (both exact)
    const float4* src = reinterpret_cast<const float4*>(conf + ((size_t)b * NUM_P + p0) * NUM_CLS);
    float4* dst = reinterpret_cast<float4*>(tile);
#pragma unroll
    for (int i = 0; i < 6; ++i) {
        int idx = tid + i * 256;
        if (idx < nf4) dst[idx] = src[idx];
    }
    __syncthreads();
    if (tid < np) {
        const int p = p0 + tid;
        const float* row = tile + tid * NUM_CLS;   // stride-21 LDS: 2-way conflict = free
        float x[NUM_CLS];
#pragma unroll
        for (int c = 0; c < NUM_CLS; ++c) x[c] = row[c];
        float m = x[0];
#pragma unroll
        for (int c = 1; c < NUM_CLS; ++c) m = fmaxf(m, x[c]);
        float e[NUM_CLS];
        float s = 0.0f;
#pragma unroll
        for (int c = 0; c < NUM_CLS; ++c) { e[c] = expf(x[c] - m); s += e[c]; }  // in-order
#pragma unroll
        for (int c = 1; c < NUM_CLS; ++c) {
            float sc = e[c] / s;
            float sv = (sc > CONF_T) ? sc : -1.0f;
            ct[((size_t)(b * 20 + (c - 1))) * NUM_P + p] = ordf(sv);
        }
    }
}

// ---------------- Kernel B: per-(image,class) exact top-200 + decode ----------------
__global__ __launch_bounds__(256) void select_kernel(const uint32_t* __restrict__ ct,
                                                     const float* __restrict__ loc,
                                                     const float* __restrict__ priors,
                                                     float* __restrict__ selS,
                                                     float* __restrict__ selX1,
                                                     float* __restrict__ selY1,
                                                     float* __restrict__ selX2,
                                                     float* __restrict__ selY2) {
    __shared__ uint32_t hist[2048];
    __shared__ uint32_t wtot[4];
    __shared__ uint32_t sh_d, sh_above, sh_bnd, sh_nsent;
    __shared__ uint64_t skey[256];
    __shared__ int scnt;
    __shared__ int sh_run;

    const int blk = blockIdx.x;
    const int b = blk / 20;
    const int tid = threadIdx.x;
    const int lane = tid & 63;
    const int wv = tid >> 6;
    const uint32_t* col = ct + (size_t)blk * NUM_P;
    const uint4* colv = reinterpret_cast<const uint4*>(col);

#pragma unroll
    for (int i = 0; i < 8; ++i) hist[tid + i * 256] = 0;
    skey[tid] = 0;
    if (tid == 0) { scnt = 0; sh_run = 0; }
    __syncthreads();

    // ---- sweep 1 (vectorized): histogram of bits [25:15] + sentinel count ----
    int nsent = 0;
#pragma unroll
    for (int i = 0; i < 9; ++i) {
        int idx = tid + i * 256;
        if (idx < NV4) {
            uint4 v = colv[idx];
            uint32_t a0 = v.x, a1 = v.y, a2 = v.z, a3 = v.w;
            if (a0 == ORD_SENT) nsent++; else atomicAdd(&hist[(a0 >> 15) & 2047u], 1u);
            if (a1 == ORD_SENT) nsent++; else atomicAdd(&hist[(a1 >> 15) & 2047u], 1u);
            if (a2 == ORD_SENT) nsent++; else atomicAdd(&hist[(a2 >> 15) & 2047u], 1u);
            if (a3 == ORD_SENT) nsent++; else atomicAdd(&hist[(a3 >> 15) & 2047u], 1u);
        }
    }
    {
        int v = nsent;
#pragma unroll
        for (int off = 32; off; off >>= 1) v += __shfl_down(v, off);
        if (lane == 0) wtot[wv] = (uint32_t)v;
        __syncthreads();
        if (tid == 0) sh_nsent = wtot[0] + wtot[1] + wtot[2] + wtot[3];
        __syncthreads();
    }
    const int nreal = NUM_P - (int)sh_nsent;

    uint32_t emitThr = 0;       // fast path: emit all o >= emitThr
    bool ranked = false;        // slow path: ranked tie resolution
    uint32_t thrEq = 0;
    int needEq = 0;

    if (nreal >= TOPK) {
        // ---- level-1 scan (2048 bins, 8/thread, suffix order) ----
        {
            const int tbase = tid * 8;
            uint32_t ls = 0;
#pragma unroll
            for (int j = 0; j < 8; ++j) ls += hist[tbase + j];
            uint32_t v = ls;
#pragma unroll
            for (int off = 1; off < 64; off <<= 1) {
                uint32_t o2 = __shfl_down(v, off);
                if (lane + off < 64) v += o2;
            }
            if (lane == 0) wtot[wv] = v;
            __syncthreads();
            uint32_t above_wave = 0;
            for (int w = wv + 1; w < 4; ++w) above_wave += wtot[w];
            uint32_t acc = (v + above_wave) - ls;
            for (int j = 7; j >= 0; --j) {
                uint32_t h = hist[tbase + j];
                if (acc < (uint32_t)TOPK && acc + h >= (uint32_t)TOPK) {
                    sh_d = (uint32_t)(tbase + j);
                    sh_above = acc;
                    sh_bnd = h;
                }
                acc += h;
            }
            __syncthreads();
        }
        uint32_t d1 = sh_d;
        int cert = (int)sh_above;
        int need = TOPK - cert;
        int bnd = (int)sh_bnd;
        const uint32_t lvl1 = HI_BITS | d1;

        if (cert + bnd <= 256) {
            emitThr = lvl1 << 15;
        } else {
            // ---- level-2: bits [14:4] among (o>>15)==lvl1 ----
            __syncthreads();
#pragma unroll
            for (int i = 0; i < 8; ++i) hist[tid + i * 256] = 0;
            __syncthreads();
#pragma unroll
            for (int i = 0; i < 9; ++i) {
                int idx = tid + i * 256;
                if (idx < NV4) {
                    uint4 v = colv[idx];
                    if ((v.x >> 15) == lvl1) atomicAdd(&hist[(v.x >> 4) & 2047u], 1u);
                    if ((v.y >> 15) == lvl1) atomicAdd(&hist[(v.y >> 4) & 2047u], 1u);
                    if ((v.z >> 15) == lvl1) atomicAdd(&hist[(v.z >> 4) & 2047u], 1u);
                    if ((v.w >> 15) == lvl1) atomicAdd(&hist[(v.w >> 4) & 2047u], 1u);
                }
            }
            __syncthreads();
            {
                const int tbase = tid * 8;
                uint32_t ls = 0;
#pragma unroll
                for (int j = 0; j < 8; ++j) ls += hist[tbase + j];
                uint32_t v = ls;
#pragma unroll
                for (int off = 1; off < 64; off <<= 1) {
                    uint32_t o2 = __shfl_down(v, off);
                    if (lane + off < 64) v += o2;
                }
                if (lane == 0) wtot[wv] = v;
                __syncthreads();
                uint32_t above_wave = 0;
                for (int w = wv + 1; w < 4; ++w) above_wave += wtot[w];
                uint32_t acc = (v + above_wave) - ls;
                for (int j = 7; j >= 0; --j) {
                    uint32_t h = hist[tbase + j];
                    if (acc < (uint32_t)need && acc + h >= (uint32_t)need) {
                        sh_d = (uint32_t)(tbase + j);
                        sh_above = acc;
                        sh_bnd = h;
                    }
                    acc += h;
                }
                __syncthreads();
            }
            uint32_t d2 = sh_d;
            cert += (int)sh_above;
            need -= (int)sh_above;
            bnd = (int)sh_bnd;
            const uint32_t pfx28 = (lvl1 << 11) | d2;

            if (cert + bnd <= 256) {
                emitThr = pfx28 << 4;
            } else {
                // ---- level-3: low 4 bits among (o>>4)==pfx28 ----
                __syncthreads();
                if (tid < 16) hist[tid] = 0;
                __syncthreads();
#pragma unroll
                for (int i = 0; i < 9; ++i) {
                    int idx = tid + i * 256;
                    if (idx < NV4) {
                        uint4 v = colv[idx];
                        if ((v.x >> 4) == pfx28) atomicAdd(&hist[v.x & 15u], 1u);
                        if ((v.y >> 4) == pfx28) atomicAdd(&hist[v.y & 15u], 1u);
                        if ((v.z >> 4) == pfx28) atomicAdd(&hist[v.z & 15u], 1u);
                        if ((v.w >> 4) == pfx28) atomicAdd(&hist[v.w & 15u], 1u);
                    }
                }
                __syncthreads();
                if (tid == 0) {
                    uint32_t acc = 0;
                    for (int j = 15; j >= 0; --j) {
                        uint32_t h = hist[j];
                        if (acc < (uint32_t)need && acc + h >= (uint32_t)need) {
                            sh_d = (uint32_t)j; sh_above = acc; sh_bnd = h; break;
                        }
                        acc += h;
                    }
                }
                __syncthreads();
                uint32_t d3 = sh_d;
                cert += (int)sh_above;
                need -= (int)sh_above;
                bnd = (int)sh_bnd;
                const uint32_t pfx32 = (pfx28 << 4) | d3;
                if (cert + bnd <= 256) {
                    emitThr = pfx32;
                } else {
                    ranked = true; thrEq = pfx32; needEq = need;
                }
            }
        }
    } else {
        ranked = true; thrEq = ORD_SENT; needEq = TOPK - nreal;
    }

    // ---- emit ----
    if (!ranked) {
#pragma unroll
        for (int i = 0; i < 9; ++i) {
            int idx = tid + i * 256;
            if (idx < NV4) {
                uint4 v = colv[idx];
                uint32_t aa[4] = {v.x, v.y, v.z, v.w};
#pragma unroll
                for (int j = 0; j < 4; ++j) {
                    uint32_t o = aa[j];
                    if (o >= emitThr) {
                        int s0 = atomicAdd(&scnt, 1);
                        uint32_t p = (uint32_t)(idx * 4 + j);
                        if (s0 < 256)
                            skey[s0] = ((uint64_t)o << 32) | (0xFFFFFFFFu - p);
                    }
                }
            }
        }
        __syncthreads();
    } else {
        // exact ranked-tie path (rare): p-ascending global order via ballot scan
        for (int i = 0; i < NL; ++i) {
            int p = i * 256 + tid;
            uint32_t o = (p < NUM_P) ? col[p] : 0u;
            if (o > thrEq) {
                int s0 = atomicAdd(&scnt, 1);
                if (s0 < 256)
                    skey[s0] = ((uint64_t)o << 32) | (0xFFFFFFFFu - (uint32_t)p);
            }
            bool tie = (p < NUM_P) && (o == thrEq);
            unsigned long long ball = __ballot(tie);
            if (lane == 0) wtot[wv] = (uint32_t)__popcll(ball);
            __syncthreads();
            int rank = sh_run;
            for (int w = 0; w < wv; ++w) rank += (int)wtot[w];
            rank += __popcll(ball & ((1ull << lane) - 1ull));
            if (tie && rank < needEq) {
                int s0 = atomicAdd(&scnt, 1);
                if (s0 < 256)
                    skey[s0] = ((uint64_t)o << 32) | (0xFFFFFFFFu - (uint32_t)p);
            }
            __syncthreads();
            if (tid == 0) sh_run += (int)(wtot[0] + wtot[1] + wtot[2] + wtot[3]);
            __syncthreads();
        }
    }

    // ---- bitonic sort 256 descending by (ordinal, p asc) key; truncate to 200 ----
    for (int k = 2; k <= 256; k <<= 1) {
        for (int j = k >> 1; j > 0; j >>= 1) {
            int ixj = tid ^ j;
            if (ixj > tid) {
                uint64_t a = skey[tid], bb = skey[ixj];
                bool up = (tid & k) == 0;
                bool sw = up ? (a < bb) : (a > bb);
                if (sw) { skey[tid] = bb; skey[ixj] = a; }
            }
            __syncthreads();
        }
    }

    // ---- decode top-200 boxes, write SoA ----
    if (tid < TOPK) {
        uint64_t k = skey[tid];
        uint32_t p = 0xFFFFFFFFu - (uint32_t)k;
        float msc = unordf((uint32_t)(k >> 32));
        const float4 l4 = reinterpret_cast<const float4*>(loc)[(size_t)b * NUM_P + p];
        const float4 pr = reinterpret_cast<const float4*>(priors)[p];
        float cx = pr.x + (l4.x * 0.1f) * pr.z;
        float cy = pr.y + (l4.y * 0.1f) * pr.w;
        float w  = pr.z * expf(l4.z * 0.2f);
        float h  = pr.w * expf(l4.w * 0.2f);
        float mx1 = cx - w * 0.5f;
        float my1 = cy - h * 0.5f;
        float mx2 = mx1 + w;
        float my2 = my1 + h;
        size_t o0 = (size_t)blk * TOPK + tid;
        selS[o0] = msc; selX1[o0] = mx1; selY1[o0] = my1; selX2[o0] = mx2; selY2[o0] = my2;
    }
}

// ---------------- Kernel C: one wave per (b,c), register NMS, zero barriers ----------------
__global__ __launch_bounds__(64) void nms_kernel(float* __restrict__ selS,
                                                 float* __restrict__ selX1,
                                                 float* __restrict__ selY1,
                                                 float* __restrict__ selX2,
                                                 float* __restrict__ selY2,
                                                 uint64_t* __restrict__ cands,
                                                 uint32_t* __restrict__ candCount) {
    const int blk = blockIdx.x;
    const int b = blk / 20;
    const int c = blk % 20;
    const int lane = threadIdx.x;
    const size_t base = (size_t)blk * TOPK;

    float scs[4], x1s[4], y1s[4], x2s[4], y2s[4], ars[4];
    uint32_t validm = 0, supm = 0;
#pragma unroll
    for (int s = 0; s < 4; ++s) {
        int idx = s * 64 + lane;
        bool v = idx < TOPK;
        scs[s] = v ? selS[base + idx] : -1.0f;
        x1s[s] = v ? selX1[base + idx] : 0.0f;
        y1s[s] = v ? selY1[base + idx] : 0.0f;
        x2s[s] = v ? selX2[base + idx] : 0.0f;
        y2s[s] = v ? selY2[base + idx] : 0.0f;
        ars[s] = (x2s[s] - x1s[s] + 1.0f) * (y2s[s] - y1s[s] + 1.0f);
        if (v && scs[s] > CONF_T) validm |= (1u << s);
    }

#pragma unroll
    for (int slot = 0; slot < 4; ++slot) {
        const int nown = (slot == 3) ? (TOPK - 3 * 64) : 64;
        for (int owner = 0; owner < nown; ++owner) {
            const int i = slot * 64 + owner;
            int myk = (int)((validm >> slot) & 1u) & (int)(((supm >> slot) & 1u) ^ 1u);
            int keep_i = __shfl(myk, owner);
            if (keep_i) {
                float bx1 = __shfl(x1s[slot], owner);
                float by1 = __shfl(y1s[slot], owner);
                float bx2 = __shfl(x2s[slot], owner);
                float by2 = __shfl(y2s[slot], owner);
                float bar_ = __shfl(ars[slot], owner);
#pragma unroll
                for (int s2 = 0; s2 < 4; ++s2) {
                    int idx = s2 * 64 + lane;
                    if (idx > i && idx < TOPK) {
                        float xx1 = fmaxf(bx1, x1s[s2]);
                        float yy1 = fmaxf(by1, y1s[s2]);
                        float xx2 = fminf(bx2, x2s[s2]);
                        float yy2 = fminf(by2, y2s[s2]);
                        float w = fmaxf(0.0f, xx2 - xx1 + 1.0f);
                        float h = fmaxf(0.0f, yy2 - yy1 + 1.0f);
                        float inter = w * h;
                        float iou = inter / (bar_ + ars[s2] - inter);
                        if (iou > NMS_T) supm |= (1u << s2);
                    }
                }
            }
        }
    }

    int off = 0;
    uint64_t wkey[4];
    int wrank[4];
    bool wk[4];
#pragma unroll
    for (int s = 0; s < 4; ++s) {
        int idx = s * 64 + lane;
        bool kept = (idx < TOPK) && ((validm >> s) & 1u) && !((supm >> s) & 1u);
        unsigned long long ball = __ballot(kept);
        int rank = off + __popcll(ball & ((1ull << lane) - 1ull));
        wk[s] = kept;
        wrank[s] = rank;
        wkey[s] = 0;
        if (kept) {
            selS[base + rank] = scs[s];
            selX1[base + rank] = x1s[s];
            selY1[base + rank] = y1s[s];
            selX2[base + rank] = x2s[s];
            selY2[base + rank] = y2s[s];
            uint32_t pos = (uint32_t)(c + 1) * TOPK + (uint32_t)rank;
            wkey[s] = ((uint64_t)ordf(scs[s]) << 32) | (uint32_t)(0xFFFFFFFFu - pos);
        }
        off += __popcll(ball);
    }
    uint32_t bcast = 0;
    if (lane == 0) bcast = atomicAdd(&candCount[b], (uint32_t)off);
    bcast = (uint32_t)__shfl((int)bcast, 0);
#pragma unroll
    for (int s = 0; s < 4; ++s)
        if (wk[s]) cands[(size_t)b * MAXCAND + bcast + wrank[s]] = wkey[s];
}

// ---------------- Kernel D: per-image final top-200, position-ordered ----------------
__global__ __launch_bounds__(256) void final_kernel(const uint64_t* __restrict__ cands,
                                                    const uint32_t* __restrict__ candCount,
                                                    const float* __restrict__ selS,
                                                    const float* __restrict__ selX1,
                                                    const float* __restrict__ selY1,
                                                    const float* __restrict__ selX2,
                                                    const float* __restrict__ selY2,
                                                    float* __restrict__ out) {
    const int b = blockIdx.x;
    const int tid = threadIdx.x;
    const int lane = tid & 63;
    const int wv = tid >> 6;
    const int n = (int)candCount[b];

    uint64_t key[NL2];
#pragma unroll
    for (int i = 0; i < NL2; ++i) {
        int idx = tid + i * 256;
        key[i] = (idx < n) ? cands[(size_t)b * MAXCAND + idx] : 0ull;
    }

    __shared__ int wsum[2][4];
    uint64_t prefix = 0;
    if (n > TOPK) {
        for (int bit = 63; bit >= 0; --bit) {
            uint64_t cand = prefix | (1ull << bit);
            int cnt = 0;
#pragma unroll
            for (int i = 0; i < NL2; ++i) cnt += (key[i] >= cand) ? 1 : 0;
            for (int off = 32; off; off >>= 1) cnt += __shfl_down(cnt, off);
            int bufi = bit & 1;
            if (lane == 0) wsum[bufi][wv] = cnt;
            __syncthreads();
            int tot = wsum[bufi][0] + wsum[bufi][1] + wsum[bufi][2] + wsum[bufi][3];
            if (tot >= TOPK) prefix = cand;
        }
    }

    __shared__ uint32_t selpos[256];
    __shared__ int scnt;
    selpos[tid] = 0xFFFFFFFFu;
    if (tid == 0) scnt = 0;
    __syncthreads();
#pragma unroll
    for (int i = 0; i < NL2; ++i)
        if (key[i] != 0ull && key[i] >= prefix) {
            int s = atomicAdd(&scnt, 1);
            selpos[s] = 0xFFFFFFFFu - (uint32_t)key[i];
        }
    __syncthreads();
    int nsel = scnt;

    for (int k = 2; k <= 256; k <<= 1) {
        for (int j = k >> 1; j > 0; j >>= 1) {
            int ixj = tid ^ j;
            if (ixj > tid) {
                uint32_t a = selpos[tid], bb = selpos[ixj];
                bool up = (tid & k) == 0;
                bool sw = up ? (a > bb) : (a < bb);
                if (sw) { selpos[tid] = bb; selpos[ixj] = a; }
            }
            __syncthreads();
        }
    }

    if (tid < TOPK) {
        int T = TOPK - (nsel < TOPK ? nsel : TOPK);
        float* o = out + ((size_t)b * TOPK + tid) * 7;
        if (tid < T) {
            o[0] = 0.f; o[1] = 0.f; o[2] = 0.f; o[3] = 0.f; o[4] = 0.f; o[5] = 0.f; o[6] = 0.f;
        } else {
            uint32_t pos = selpos[tid - T];
            uint32_t cc = pos / TOPK;
            uint32_t sl = pos % TOPK;
            size_t r = ((size_t)b * 20 + (cc - 1)) * TOPK + sl;
            o[0] = selS[r]; o[1] = selX1[r]; o[2] = selY1[r]; o[3] = selX2[r]; o[4] = selY2[r];
            o[5] = 0.f; o[6] = 0.f;
        }
    }
}

extern "C" void kernel_launch(void* const* d_in, const int* in_sizes, int n_in,
                              void* d_out, int out_size, void* d_ws, size_t ws_size,
                              hipStream_t stream) {
    const float* loc    = (const float*)d_in[0];
    const float* conf   = (const float*)d_in[1];
    const float* priors = (const float*)d_in[2];
    float* out = (float*)d_out;

    const size_t CAND_BYTES = (size_t)NUM_B * MAXCAND * sizeof(uint64_t);   // 2,048,000
    const size_t SEL_ONE    = (size_t)NUM_B * 20 * TOPK * sizeof(float);    // 1,024,000
    const size_t CNT_BYTES  = 256;

    char* ws = (char*)d_ws;
    uint64_t* cands     = (uint64_t*)ws;
    float*    selS      = (float*)(ws + CAND_BYTES);
    float*    selX1     = (float*)(ws + CAND_BYTES + SEL_ONE);
    float*    selY1     = (float*)(ws + CAND_BYTES + 2 * SEL_ONE);
    float*    selX2     = (float*)(ws + CAND_BYTES + 3 * SEL_ONE);
    float*    selY2     = (float*)(ws + CAND_BYTES + 4 * SEL_ONE);
    uint32_t* candCount = (uint32_t*)(ws + CAND_BYTES + 5 * SEL_ONE);
    uint32_t* ct        = (uint32_t*)(ws + CAND_BYTES + 5 * SEL_ONE + CNT_BYTES);

    dim3 pgrid((NUM_P + 255) / 256, NUM_B);
    prep_kernel<<<pgrid, 256, 0, stream>>>(conf, ct, candCount);
    select_kernel<<<NUM_B * 20, 256, 0, stream>>>(ct, loc, priors,
                                                  selS, selX1, selY1, selX2, selY2);
    nms_kernel<<<NUM_B * 20, 64, 0, stream>>>(selS, selX1, selY1, selX2, selY2,
                                              cands, candCount);
    final_kernel<<<NUM_B, 256, 0, stream>>>(cands, candCount,
                                            selS, selX1, selY1, selX2, selY2, out);
}

// Round 5
// 69.990 us; speedup vs baseline: 2.9480x; 1.1352x over previous
//
#include <hip/hip_runtime.h>
#include <stdint.h>

#define NUM_P 8732
#define NUM_B 64
#define NUM_CLS 21
#define TOPK 200
#define NMS_T 0.45f
#define CONF_T 0.01f
#define NL 35               // ceil(8732/256) scalar sweep iters
#define NV4 2183            // 8732/4 uint4 sweep elements
#define NL2 16              // ceil(4000/256)
#define MAXCAND 4000
#define ORD_SENT 0x407FFFFFu   // ordf(-1.0f)
#define HI_BITS 0x17800u       // (o>>15) high part common to all real scores (o>>26==47)

__device__ __forceinline__ uint32_t ordf(float f) {
    uint32_t u = __float_as_uint(f);
    return (u & 0x80000000u) ? ~u : (u | 0x80000000u);
}
__device__ __forceinline__ float unordf(uint32_t v) {
    uint32_t u = (v & 0x80000000u) ? (v ^ 0x80000000u) : ~v;
    return __uint_as_float(u);
}

// ---------------- Kernel A: softmax -> transposed score ordinals (LDS-staged) --------
__global__ __launch_bounds__(256) void prep_kernel(const float* __restrict__ conf,
                                                   uint32_t* __restrict__ ct,
                                                   uint32_t* __restrict__ candCount) {
    __shared__ float tile[256 * NUM_CLS];   // 21504 B
    const int bx = blockIdx.x;
    const int b = blockIdx.y;
    const int tid = threadIdx.x;
    if (bx == 0 && b == 0 && tid < NUM_B) candCount[tid] = 0u;
    const int p0 = bx * 256;
    const int np = min(256, NUM_P - p0);
    const int nf4 = (np * NUM_CLS) / 4;     // 1344 or 147 (both exact)
    const float4* src = reinterpret_cast<const float4*>(conf + ((size_t)b * NUM_P + p0) * NUM_CLS);
    float4* dst = reinterpret_cast<float4*>(tile);
#pragma unroll
    for (int i = 0; i < 6; ++i) {
        int idx = tid + i * 256;
        if (idx < nf4) dst[idx] = src[idx];
    }
    __syncthreads();
    if (tid < np) {
        const int p = p0 + tid;
        const float* row = tile + tid * NUM_CLS;   // stride-21 LDS: 2-way conflict = free
        float x[NUM_CLS];
#pragma unroll
        for (int c = 0; c < NUM_CLS; ++c) x[c] = row[c];
        float m = x[0];
#pragma unroll
        for (int c = 1; c < NUM_CLS; ++c) m = fmaxf(m, x[c]);
        float e[NUM_CLS];
        float s = 0.0f;
#pragma unroll
        for (int c = 0; c < NUM_CLS; ++c) { e[c] = expf(x[c] - m); s += e[c]; }  // in-order
#pragma unroll
        for (int c = 1; c < NUM_CLS; ++c) {
            float sc = e[c] / s;
            float sv = (sc > CONF_T) ? sc : -1.0f;
            ct[((size_t)(b * 20 + (c - 1))) * NUM_P + p] = ordf(sv);
        }
    }
}

// ------- Kernel B: per-(image,class) exact top-200 + decode + fused wave-0 NMS -------
__global__ __launch_bounds__(256, 4) void select_nms_kernel(const uint32_t* __restrict__ ct,
                                                            const float* __restrict__ loc,
                                                            const float* __restrict__ priors,
                                                            float* __restrict__ selS,
                                                            float* __restrict__ selX1,
                                                            float* __restrict__ selY1,
                                                            float* __restrict__ selX2,
                                                            float* __restrict__ selY2,
                                                            uint64_t* __restrict__ cands,
                                                            uint32_t* __restrict__ candCount) {
    __shared__ uint32_t hist[2048];
    __shared__ uint32_t wtot[4];
    __shared__ uint32_t sh_d, sh_above, sh_bnd, sh_nsent;
    __shared__ uint64_t skey[256];
    __shared__ int scnt;
    __shared__ int sh_run;

    const int blk = blockIdx.x;
    const int b = blk / 20;
    const int c = blk % 20;
    const int tid = threadIdx.x;
    const int lane = tid & 63;
    const int wv = tid >> 6;
    const uint32_t* col = ct + (size_t)blk * NUM_P;
    const uint4* colv = reinterpret_cast<const uint4*>(col);

#pragma unroll
    for (int i = 0; i < 8; ++i) hist[tid + i * 256] = 0;
    skey[tid] = 0;
    if (tid == 0) { scnt = 0; sh_run = 0; }
    __syncthreads();

    // ---- single global sweep into registers; histogram bits [25:15] + sentinels ----
    uint4 vv[9];
#pragma unroll
    for (int i = 0; i < 9; ++i) {
        int idx = tid + i * 256;
        vv[i] = make_uint4(ORD_SENT, ORD_SENT, ORD_SENT, ORD_SENT);
        if (idx < NV4) vv[i] = colv[idx];
    }
    int nsent = 0;
#pragma unroll
    for (int i = 0; i < 9; ++i) {
        int idx = tid + i * 256;
        if (idx < NV4) {
            uint32_t a0 = vv[i].x, a1 = vv[i].y, a2 = vv[i].z, a3 = vv[i].w;
            if (a0 == ORD_SENT) nsent++; else atomicAdd(&hist[(a0 >> 15) & 2047u], 1u);
            if (a1 == ORD_SENT) nsent++; else atomicAdd(&hist[(a1 >> 15) & 2047u], 1u);
            if (a2 == ORD_SENT) nsent++; else atomicAdd(&hist[(a2 >> 15) & 2047u], 1u);
            if (a3 == ORD_SENT) nsent++; else atomicAdd(&hist[(a3 >> 15) & 2047u], 1u);
        }
    }
    {
        int v = nsent;
#pragma unroll
        for (int off = 32; off; off >>= 1) v += __shfl_down(v, off);
        if (lane == 0) wtot[wv] = (uint32_t)v;
        __syncthreads();
        if (tid == 0) sh_nsent = wtot[0] + wtot[1] + wtot[2] + wtot[3];
        __syncthreads();
    }
    const int nreal = NUM_P - (int)sh_nsent;

    uint32_t emitThr = 0;
    bool ranked = false;
    uint32_t thrEq = 0;
    int needEq = 0;

    if (nreal >= TOPK) {
        // ---- level-1 scan (2048 bins, 8/thread, suffix order) ----
        {
            const int tbase = tid * 8;
            uint32_t ls = 0;
#pragma unroll
            for (int j = 0; j < 8; ++j) ls += hist[tbase + j];
            uint32_t v = ls;
#pragma unroll
            for (int off = 1; off < 64; off <<= 1) {
                uint32_t o2 = __shfl_down(v, off);
                if (lane + off < 64) v += o2;
            }
            if (lane == 0) wtot[wv] = v;
            __syncthreads();
            uint32_t above_wave = 0;
            for (int w = wv + 1; w < 4; ++w) above_wave += wtot[w];
            uint32_t acc = (v + above_wave) - ls;
            for (int j = 7; j >= 0; --j) {
                uint32_t h = hist[tbase + j];
                if (acc < (uint32_t)TOPK && acc + h >= (uint32_t)TOPK) {
                    sh_d = (uint32_t)(tbase + j);
                    sh_above = acc;
                    sh_bnd = h;
                }
                acc += h;
            }
            __syncthreads();
        }
        uint32_t d1 = sh_d;
        int cert = (int)sh_above;
        int need = TOPK - cert;
        int bnd = (int)sh_bnd;
        const uint32_t lvl1 = HI_BITS | d1;

        if (cert + bnd <= 256) {
            emitThr = lvl1 << 15;
        } else {
            // ---- level-2: bits [14:4] among (o>>15)==lvl1 (from registers) ----
            __syncthreads();
#pragma unroll
            for (int i = 0; i < 8; ++i) hist[tid + i * 256] = 0;
            __syncthreads();
#pragma unroll
            for (int i = 0; i < 9; ++i) {
                int idx = tid + i * 256;
                if (idx < NV4) {
                    if ((vv[i].x >> 15) == lvl1) atomicAdd(&hist[(vv[i].x >> 4) & 2047u], 1u);
                    if ((vv[i].y >> 15) == lvl1) atomicAdd(&hist[(vv[i].y >> 4) & 2047u], 1u);
                    if ((vv[i].z >> 15) == lvl1) atomicAdd(&hist[(vv[i].z >> 4) & 2047u], 1u);
                    if ((vv[i].w >> 15) == lvl1) atomicAdd(&hist[(vv[i].w >> 4) & 2047u], 1u);
                }
            }
            __syncthreads();
            {
                const int tbase = tid * 8;
                uint32_t ls = 0;
#pragma unroll
                for (int j = 0; j < 8; ++j) ls += hist[tbase + j];
                uint32_t v = ls;
#pragma unroll
                for (int off = 1; off < 64; off <<= 1) {
                    uint32_t o2 = __shfl_down(v, off);
                    if (lane + off < 64) v += o2;
                }
                if (lane == 0) wtot[wv] = v;
                __syncthreads();
                uint32_t above_wave = 0;
                for (int w = wv + 1; w < 4; ++w) above_wave += wtot[w];
                uint32_t acc = (v + above_wave) - ls;
                for (int j = 7; j >= 0; --j) {
                    uint32_t h = hist[tbase + j];
                    if (acc < (uint32_t)need && acc + h >= (uint32_t)need) {
                        sh_d = (uint32_t)(tbase + j);
                        sh_above = acc;
                        sh_bnd = h;
                    }
                    acc += h;
                }
                __syncthreads();
            }
            uint32_t d2 = sh_d;
            cert += (int)sh_above;
            need -= (int)sh_above;
            bnd = (int)sh_bnd;
            const uint32_t pfx28 = (lvl1 << 11) | d2;

            if (cert + bnd <= 256) {
                emitThr = pfx28 << 4;
            } else {
                // ---- level-3: low 4 bits among (o>>4)==pfx28 ----
                __syncthreads();
                if (tid < 16) hist[tid] = 0;
                __syncthreads();
#pragma unroll
                for (int i = 0; i < 9; ++i) {
                    int idx = tid + i * 256;
                    if (idx < NV4) {
                        if ((vv[i].x >> 4) == pfx28) atomicAdd(&hist[vv[i].x & 15u], 1u);
                        if ((vv[i].y >> 4) == pfx28) atomicAdd(&hist[vv[i].y & 15u], 1u);
                        if ((vv[i].z >> 4) == pfx28) atomicAdd(&hist[vv[i].z & 15u], 1u);
                        if ((vv[i].w >> 4) == pfx28) atomicAdd(&hist[vv[i].w & 15u], 1u);
                    }
                }
                __syncthreads();
                if (tid == 0) {
                    uint32_t acc = 0;
                    for (int j = 15; j >= 0; --j) {
                        uint32_t h = hist[j];
                        if (acc < (uint32_t)need && acc + h >= (uint32_t)need) {
                            sh_d = (uint32_t)j; sh_above = acc; sh_bnd = h; break;
                        }
                        acc += h;
                    }
                }
                __syncthreads();
                uint32_t d3 = sh_d;
                cert += (int)sh_above;
                need -= (int)sh_above;
                bnd = (int)sh_bnd;
                const uint32_t pfx32 = (pfx28 << 4) | d3;
                if (cert + bnd <= 256) {
                    emitThr = pfx32;
                } else {
                    ranked = true; thrEq = pfx32; needEq = need;
                }
            }
        }
    } else {
        ranked = true; thrEq = ORD_SENT; needEq = TOPK - nreal;
    }

    // ---- emit ----
    if (!ranked) {
#pragma unroll
        for (int i = 0; i < 9; ++i) {
            int idx = tid + i * 256;
            if (idx < NV4) {
                uint32_t aa[4] = {vv[i].x, vv[i].y, vv[i].z, vv[i].w};
#pragma unroll
                for (int j = 0; j < 4; ++j) {
                    uint32_t o = aa[j];
                    if (o >= emitThr) {
                        int s0 = atomicAdd(&scnt, 1);
                        uint32_t p = (uint32_t)(idx * 4 + j);
                        if (s0 < 256)
                            skey[s0] = ((uint64_t)o << 32) | (0xFFFFFFFFu - p);
                    }
                }
            }
        }
        __syncthreads();
    } else {
        // exact ranked-tie path (rare): p-ascending global order via ballot scan
        for (int i = 0; i < NL; ++i) {
            int p = i * 256 + tid;
            uint32_t o = (p < NUM_P) ? col[p] : 0u;
            if (o > thrEq) {
                int s0 = atomicAdd(&scnt, 1);
                if (s0 < 256)
                    skey[s0] = ((uint64_t)o << 32) | (0xFFFFFFFFu - (uint32_t)p);
            }
            bool tie = (p < NUM_P) && (o == thrEq);
            unsigned long long ball = __ballot(tie);
            if (lane == 0) wtot[wv] = (uint32_t)__popcll(ball);
            __syncthreads();
            int rank = sh_run;
            for (int w = 0; w < wv; ++w) rank += (int)wtot[w];
            rank += __popcll(ball & ((1ull << lane) - 1ull));
            if (tie && rank < needEq) {
                int s0 = atomicAdd(&scnt, 1);
                if (s0 < 256)
                    skey[s0] = ((uint64_t)o << 32) | (0xFFFFFFFFu - (uint32_t)p);
            }
            __syncthreads();
            if (tid == 0) sh_run += (int)(wtot[0] + wtot[1] + wtot[2] + wtot[3]);
            __syncthreads();
        }
    }

    // ---- bitonic sort 256 descending by (ordinal, p asc) key ----
    for (int k = 2; k <= 256; k <<= 1) {
        for (int j = k >> 1; j > 0; j >>= 1) {
            int ixj = tid ^ j;
            if (ixj > tid) {
                uint64_t a = skey[tid], bb = skey[ixj];
                bool up = (tid & k) == 0;
                bool sw = up ? (a < bb) : (a > bb);
                if (sw) { skey[tid] = bb; skey[ixj] = a; }
            }
            __syncthreads();
        }
    }

    // ---- decode top-200 into LDS (reuse hist: 6*200 floats = 4800 B < 8192 B) ----
    float* nb = reinterpret_cast<float*>(hist);
    float* dsc = nb;
    float* dx1 = nb + TOPK;
    float* dy1 = nb + 2 * TOPK;
    float* dx2 = nb + 3 * TOPK;
    float* dy2 = nb + 4 * TOPK;
    float* dar = nb + 5 * TOPK;
    if (tid < TOPK) {
        uint64_t k = skey[tid];
        uint32_t p = 0xFFFFFFFFu - (uint32_t)k;
        float msc = unordf((uint32_t)(k >> 32));
        const float4 l4 = reinterpret_cast<const float4*>(loc)[(size_t)b * NUM_P + p];
        const float4 pr = reinterpret_cast<const float4*>(priors)[p];
        float cx = pr.x + (l4.x * 0.1f) * pr.z;
        float cy = pr.y + (l4.y * 0.1f) * pr.w;
        float w  = pr.z * expf(l4.z * 0.2f);
        float h  = pr.w * expf(l4.w * 0.2f);
        float mx1 = cx - w * 0.5f;
        float my1 = cy - h * 0.5f;
        float mx2 = mx1 + w;
        float my2 = my1 + h;
        dsc[tid] = msc; dx1[tid] = mx1; dy1[tid] = my1; dx2[tid] = mx2; dy2[tid] = my2;
        dar[tid] = (mx2 - mx1 + 1.0f) * (my2 - my1 + 1.0f);
    }
    __syncthreads();
    if (wv != 0) return;    // waves 1-3 done; wave 0 runs the barrier-free NMS

    float scs[4], x1s[4], y1s[4], x2s[4], y2s[4], ars[4];
    uint32_t validm = 0, supm = 0;
#pragma unroll
    for (int s = 0; s < 4; ++s) {
        int idx = s * 64 + lane;
        bool v = idx < TOPK;
        scs[s] = v ? dsc[idx] : -1.0f;
        x1s[s] = v ? dx1[idx] : 0.0f;
        y1s[s] = v ? dy1[idx] : 0.0f;
        x2s[s] = v ? dx2[idx] : 0.0f;
        y2s[s] = v ? dy2[idx] : 0.0f;
        ars[s] = v ? dar[idx] : 1.0f;
        if (v && scs[s] > CONF_T) validm |= (1u << s);
    }

#pragma unroll
    for (int slot = 0; slot < 4; ++slot) {
        const int nown = (slot == 3) ? (TOPK - 3 * 64) : 64;   // 200 = 3*64 + 8
        for (int owner = 0; owner < nown; ++owner) {
            const int i = slot * 64 + owner;
            int myk = (int)((validm >> slot) & 1u) & (int)(((supm >> slot) & 1u) ^ 1u);
            int keep_i = __shfl(myk, owner);
            if (keep_i) {   // wave-uniform branch
                float bx1 = __shfl(x1s[slot], owner);
                float by1 = __shfl(y1s[slot], owner);
                float bx2 = __shfl(x2s[slot], owner);
                float by2 = __shfl(y2s[slot], owner);
                float bar_ = __shfl(ars[slot], owner);
#pragma unroll
                for (int s2 = 0; s2 < 4; ++s2) {
                    int idx = s2 * 64 + lane;
                    if (idx > i && idx < TOPK) {
                        float xx1 = fmaxf(bx1, x1s[s2]);
                        float yy1 = fmaxf(by1, y1s[s2]);
                        float xx2 = fminf(bx2, x2s[s2]);
                        float yy2 = fminf(by2, y2s[s2]);
                        float w = fmaxf(0.0f, xx2 - xx1 + 1.0f);
                        float h = fmaxf(0.0f, yy2 - yy1 + 1.0f);
                        float inter = w * h;
                        float iou = inter / (bar_ + ars[s2] - inter);
                        if (iou > NMS_T) supm |= (1u << s2);
                    }
                }
            }
        }
    }

    // ---- compact kept rows in index order; write rows + per-image candidates ----
    const size_t base = (size_t)blk * TOPK;
    int off = 0;
    uint64_t wkey[4];
    int wrank[4];
    bool wk[4];
#pragma unroll
    for (int s = 0; s < 4; ++s) {
        int idx = s * 64 + lane;
        bool kept = (idx < TOPK) && ((validm >> s) & 1u) && !((supm >> s) & 1u);
        unsigned long long ball = __ballot(kept);
        int rank = off + __popcll(ball & ((1ull << lane) - 1ull));
        wk[s] = kept;
        wrank[s] = rank;
        wkey[s] = 0;
        if (kept) {
            selS[base + rank] = scs[s];
            selX1[base + rank] = x1s[s];
            selY1[base + rank] = y1s[s];
            selX2[base + rank] = x2s[s];
            selY2[base + rank] = y2s[s];
            uint32_t pos = (uint32_t)(c + 1) * TOPK + (uint32_t)rank;
            wkey[s] = ((uint64_t)ordf(scs[s]) << 32) | (uint32_t)(0xFFFFFFFFu - pos);
        }
        off += __popcll(ball);
    }
    uint32_t bcast = 0;
    if (lane == 0) bcast = atomicAdd(&candCount[b], (uint32_t)off);
    bcast = (uint32_t)__shfl((int)bcast, 0);
#pragma unroll
    for (int s = 0; s < 4; ++s)
        if (wk[s]) cands[(size_t)b * MAXCAND + bcast + wrank[s]] = wkey[s];
}

// ---------------- Kernel C: per-image final top-200, position-ordered ----------------
__global__ __launch_bounds__(256) void final_kernel(const uint64_t* __restrict__ cands,
                                                    const uint32_t* __restrict__ candCount,
                                                    const float* __restrict__ selS,
                                                    const float* __restrict__ selX1,
                                                    const float* __restrict__ selY1,
                                                    const float* __restrict__ selX2,
                                                    const float* __restrict__ selY2,
                                                    float* __restrict__ out) {
    const int b = blockIdx.x;
    const int tid = threadIdx.x;
    const int lane = tid & 63;
    const int wv = tid >> 6;
    const int n = (int)candCount[b];

    uint64_t key[NL2];
#pragma unroll
    for (int i = 0; i < NL2; ++i) {
        int idx = tid + i * 256;
        key[i] = (idx < n) ? cands[(size_t)b * MAXCAND + idx] : 0ull;
    }

    __shared__ int wsum[2][4];
    uint64_t prefix = 0;
    if (n > TOPK) {
        for (int bit = 63; bit >= 0; --bit) {
            uint64_t cand = prefix | (1ull << bit);
            int cnt = 0;
#pragma unroll
            for (int i = 0; i < NL2; ++i) cnt += (key[i] >= cand) ? 1 : 0;
            for (int off = 32; off; off >>= 1) cnt += __shfl_down(cnt, off);
            int bufi = bit & 1;
            if (lane == 0) wsum[bufi][wv] = cnt;
            __syncthreads();
            int tot = wsum[bufi][0] + wsum[bufi][1] + wsum[bufi][2] + wsum[bufi][3];
            if (tot >= TOPK) prefix = cand;
        }
    }

    __shared__ uint32_t selpos[256];
    __shared__ int scnt;
    selpos[tid] = 0xFFFFFFFFu;
    if (tid == 0) scnt = 0;
    __syncthreads();
#pragma unroll
    for (int i = 0; i < NL2; ++i)
        if (key[i] != 0ull && key[i] >= prefix) {
            int s = atomicAdd(&scnt, 1);
            selpos[s] = 0xFFFFFFFFu - (uint32_t)key[i];
        }
    __syncthreads();
    int nsel = scnt;

    for (int k = 2; k <= 256; k <<= 1) {
        for (int j = k >> 1; j > 0; j >>= 1) {
            int ixj = tid ^ j;
            if (ixj > tid) {
                uint32_t a = selpos[tid], bb = selpos[ixj];
                bool up = (tid & k) == 0;
                bool sw = up ? (a > bb) : (a < bb);
                if (sw) { selpos[tid] = bb; selpos[ixj] = a; }
            }
            __syncthreads();
        }
    }

    if (tid < TOPK) {
        int T = TOPK - (nsel < TOPK ? nsel : TOPK);
        float* o = out + ((size_t)b * TOPK + tid) * 7;
        if (tid < T) {
            o[0] = 0.f; o[1] = 0.f; o[2] = 0.f; o[3] = 0.f; o[4] = 0.f; o[5] = 0.f; o[6] = 0.f;
        } else {
            uint32_t pos = selpos[tid - T];
            uint32_t cc = pos / TOPK;
            uint32_t sl = pos % TOPK;
            size_t r = ((size_t)b * 20 + (cc - 1)) * TOPK + sl;
            o[0] = selS[r]; o[1] = selX1[r]; o[2] = selY1[r]; o[3] = selX2[r]; o[4] = selY2[r];
            o[5] = 0.f; o[6] = 0.f;
        }
    }
}

extern "C" void kernel_launch(void* const* d_in, const int* in_sizes, int n_in,
                              void* d_out, int out_size, void* d_ws, size_t ws_size,
                              hipStream_t stream) {
    const float* loc    = (const float*)d_in[0];
    const float* conf   = (const float*)d_in[1];
    const float* priors = (const float*)d_in[2];
    float* out = (float*)d_out;

    const size_t CAND_BYTES = (size_t)NUM_B * MAXCAND * sizeof(uint64_t);   // 2,048,000
    const size_t SEL_ONE    = (size_t)NUM_B * 20 * TOPK * sizeof(float);    // 1,024,000
    const size_t CNT_BYTES  = 256;

    char* ws = (char*)d_ws;
    uint64_t* cands     = (uint64_t*)ws;
    float*    selS      = (float*)(ws + CAND_BYTES);
    float*    selX1     = (float*)(ws + CAND_BYTES + SEL_ONE);
    float*    selY1     = (float*)(ws + CAND_BYTES + 2 * SEL_ONE);
    float*    selX2     = (float*)(ws + CAND_BYTES + 3 * SEL_ONE);
    float*    selY2     = (float*)(ws + CAND_BYTES + 4 * SEL_ONE);
    uint32_t* candCount = (uint32_t*)(ws + CAND_BYTES + 5 * SEL_ONE);
    uint32_t* ct        = (uint32_t*)(ws + CAND_BYTES + 5 * SEL_ONE + CNT_BYTES);

    dim3 pgrid((NUM_P + 255) / 256, NUM_B);
    prep_kernel<<<pgrid, 256, 0, stream>>>(conf, ct, candCount);
    select_nms_kernel<<<NUM_B * 20, 256, 0, stream>>>(ct, loc, priors,
                                                      selS, selX1, selY1, selX2, selY2,
                                                      cands, candCount);
    final_kernel<<<NUM_B, 256, 0, stream>>>(cands, candCount,
                                            selS, selX1, selY1, selX2, selY2, out);
}